// Round 6
// baseline (5015.174 us; speedup 1.0000x reference)
//
#include <hip/hip_runtime.h>

#define NTOK   16384
#define INF    2048
#define OUTF   2048
#define RANK   45
#define GTOK   8
#define NRULES 64

// ---------------- Kernel 0: sort tokens by rule (single block) ----------------
__global__ __launch_bounds__(1024) void sort_kernel(
    const int* __restrict__ rid, int* __restrict__ perm)
{
    __shared__ int cnt[NRULES];
    __shared__ int cur[NRULES];
    const int tid = threadIdx.x;
    if (tid < NRULES) cnt[tid] = 0;
    __syncthreads();
    for (int i = tid; i < NTOK; i += 1024) atomicAdd(&cnt[rid[i]], 1);
    __syncthreads();
    if (tid == 0) {
        int s = 0;
        for (int r = 0; r < NRULES; ++r) { cur[r] = s; s += cnt[r]; }
    }
    __syncthreads();
    for (int i = tid; i < NTOK; i += 1024) {
        const int r = rid[i];
        const int p = atomicAdd(&cur[r], 1);
        perm[p] = i;
    }
}

// ---------------- Kernel A: t = x @ shared_in  [16384,2048]@[2048,45] ----------------
// (round-3 t_gemm2, measured ~218us) 256 blocks x 512 thr; 64r x 48c; micro 2r x 3c.
__global__ __launch_bounds__(512) void t_gemm2(
    const float* __restrict__ x, const float* __restrict__ si, float* __restrict__ t)
{
    __shared__ float x_t[64][66];
    __shared__ float si_l[64][48];
    const int tid  = threadIdx.x;
    const int rg   = tid & 31, cg = tid >> 5;
    const int row0 = rg * 2, c0 = cg * 3;
    const float4* __restrict__ xg = (const float4*)(x + (size_t)blockIdx.x * 64 * INF);

    if (tid < 64 * 3) si_l[tid / 3][RANK + tid % 3] = 0.f;

    float a00=0.f,a01=0.f,a02=0.f,a10=0.f,a11=0.f,a12=0.f;
    float4 px[2];
    float  ps[6];

#pragma unroll
    for (int s = 0; s < 2; ++s) {
        const int i4 = tid + s * 512;
        px[s] = xg[(i4 >> 4) * (INF / 4) + (i4 & 15)];
    }
#pragma unroll
    for (int s = 0; s < 6; ++s) {
        const int i = tid + s * 512;
        ps[s] = (i < 64 * RANK) ? si[i] : 0.f;
    }

    for (int ch = 0; ch < INF / 64; ++ch) {
#pragma unroll
        for (int s = 0; s < 2; ++s) {
            const int i4 = tid + s * 512;
            const int r = i4 >> 4, kq = (i4 & 15) * 4;
            x_t[kq][r] = px[s].x; x_t[kq + 1][r] = px[s].y;
            x_t[kq + 2][r] = px[s].z; x_t[kq + 3][r] = px[s].w;
        }
#pragma unroll
        for (int s = 0; s < 6; ++s) {
            const int i = tid + s * 512;
            if (i < 64 * RANK) si_l[i / RANK][i % RANK] = ps[s];
        }
        __syncthreads();
        if (ch + 1 < INF / 64) {
            const int k0 = (ch + 1) * 64;
#pragma unroll
            for (int s = 0; s < 2; ++s) {
                const int i4 = tid + s * 512;
                px[s] = xg[(i4 >> 4) * (INF / 4) + (k0 >> 2) + (i4 & 15)];
            }
#pragma unroll
            for (int s = 0; s < 6; ++s) {
                const int i = tid + s * 512;
                ps[s] = (i < 64 * RANK) ? si[(size_t)k0 * RANK + i] : 0.f;
            }
        }
#pragma unroll 4
        for (int k = 0; k < 64; ++k) {
            const float2 xv = *(const float2*)&x_t[k][row0];
            const float s0 = si_l[k][c0], s1 = si_l[k][c0 + 1], s2 = si_l[k][c0 + 2];
            a00 += xv.x * s0; a01 += xv.x * s1; a02 += xv.x * s2;
            a10 += xv.y * s0; a11 += xv.y * s1; a12 += xv.y * s2;
        }
        __syncthreads();
    }

    if (c0 < RANK) {
        float* __restrict__ t0 = t + ((size_t)blockIdx.x * 64 + row0) * RANK + c0;
        t0[0] = a00; t0[1] = a01; t0[2] = a02;
        t0[RANK] = a10; t0[RANK + 1] = a11; t0[RANK + 2] = a12;
    }
}

// ---------------- Kernel B: out[perm] = t[perm]@so + gain * vec(V x U^T) ----------------
// Round-2 proven structure (direct global->LDS staging, NO reg prefetch) + sorted
// tokens: U/V staged only on rule change (~1/8 of blocks' tokens).
__global__ __launch_bounds__(256) void fused4(
    const float* __restrict__ x, const int* __restrict__ rid_p,
    const float* __restrict__ so, const float* __restrict__ rU,
    const float* __restrict__ rV, const float* __restrict__ gains,
    const float* __restrict__ t, const int* __restrict__ perm, float* __restrict__ out)
{
    __shared__ __align__(16) float x_lds[INF];
    __shared__ __align__(16) float xu_t[32][68];
    __shared__ __align__(16) float U_t[32][33];
    __shared__ __align__(16) float V_lds[64][68];
    __shared__ float t_lds[GTOK][RANK + 1];
    __shared__ int   sperm[GTOK], srid[GTOK];
    __shared__ float sgain[GTOK];

    const int tid  = threadIdx.x;
    const int p0   = blockIdx.x * GTOK;
    const int c0   = tid & 15;
    const int dgrp = tid >> 4;
    const int cx   = tid & 31;
    const int bg   = tid >> 5;

    if (tid < GTOK) {
        const int i = perm[p0 + tid];
        sperm[tid] = i;
        const int r = rid_p[i];
        srid[tid]  = r;
        sgain[tid] = gains[r];
    }
    __syncthreads();

    for (int i2 = tid; i2 < GTOK * RANK; i2 += 256) {
        const int g = i2 / RANK, r = i2 - g * RANK;
        t_lds[g][r] = t[(size_t)sperm[g] * RANK + r];
    }

    float acc[GTOK][8];
#pragma unroll
    for (int g = 0; g < GTOK; ++g)
#pragma unroll
        for (int j = 0; j < 8; ++j) acc[g][j] = 0.f;

    __syncthreads();

    // ---- base: acc[g][j] += sum_k t[g][k] * so[k][col_j]
    for (int k = 0; k < RANK; ++k) {
        float sv[8];
#pragma unroll
        for (int jd = 0; jd < 4; ++jd)
#pragma unroll
            for (int jc = 0; jc < 2; ++jc)
                sv[jd * 2 + jc] = so[(size_t)k * OUTF + (dgrp + 16 * jd) * 32 + c0 + 16 * jc];
#pragma unroll
        for (int g = 0; g < GTOK; ++g) {
            const float tv = t_lds[g][k];
#pragma unroll
            for (int j = 0; j < 8; ++j) acc[g][j] += tv * sv[j];
        }
    }

    // ---- adapter (direct load->LDS staging, short live ranges)
#pragma unroll
    for (int g = 0; g < GTOK; ++g) {
        const float* __restrict__ xr = x + (size_t)sperm[g] * INF;

        __syncthreads();   // previous token's LDS readers done
        ((float4*)x_lds)[tid]       = ((const float4*)xr)[tid];
        ((float4*)x_lds)[tid + 256] = ((const float4*)xr)[tid + 256];
        const bool newrule = (g == 0) || (srid[g] != srid[g - 1]);   // block-uniform
        if (newrule) {
            const float* __restrict__ Ur = rU + (size_t)srid[g] * 1024;
            const float* __restrict__ Vr = rV + (size_t)srid[g] * 4096;
#pragma unroll
            for (int i = 0; i < 4; ++i) {
                const int ii = tid + i * 256;
                U_t[ii & 31][ii >> 5] = Ur[ii];
            }
#pragma unroll
            for (int i = 0; i < 4; ++i) {
                const int i4 = tid + i * 256;
                *(float4*)&V_lds[i4 >> 4][(i4 & 15) * 4] = ((const float4*)Vr)[i4];
            }
        }
        __syncthreads();

        // xu[b][cx] = sum_a x[b*32+a] * U[cx][a],  b = bg*8 + jj
        float xacc[8];
#pragma unroll
        for (int jj = 0; jj < 8; ++jj) xacc[jj] = 0.f;
        for (int aa = 0; aa < 32; aa += 4) {
            const float u0 = U_t[aa][cx], u1 = U_t[aa + 1][cx];
            const float u2 = U_t[aa + 2][cx], u3 = U_t[aa + 3][cx];
#pragma unroll
            for (int jj = 0; jj < 8; ++jj) {
                const float4 xv = *(const float4*)&x_lds[(bg * 8 + jj) * 32 + aa];
                xacc[jj] += xv.x * u0 + xv.y * u1 + xv.z * u2 + xv.w * u3;
            }
        }
#pragma unroll
        for (int jj = 0; jj < 8; ++jj) xu_t[cx][bg * 8 + jj] = xacc[jj];
        __syncthreads();

        // vxu[d][c] = sum_b V[d][b] * xu[b][c]
        float vtmp[8];
#pragma unroll
        for (int j = 0; j < 8; ++j) vtmp[j] = 0.f;
        for (int b = 0; b < 64; b += 4) {
            const float4 xc0 = *(const float4*)&xu_t[c0][b];
            const float4 xc1 = *(const float4*)&xu_t[c0 + 16][b];
#pragma unroll
            for (int jd = 0; jd < 4; ++jd) {
                const float4 vv = *(const float4*)&V_lds[dgrp + 16 * jd][b];
                vtmp[jd * 2]     += vv.x * xc0.x + vv.y * xc0.y + vv.z * xc0.z + vv.w * xc0.w;
                vtmp[jd * 2 + 1] += vv.x * xc1.x + vv.y * xc1.y + vv.z * xc1.z + vv.w * xc1.w;
            }
        }
#pragma unroll
        for (int j = 0; j < 8; ++j) acc[g][j] += sgain[g] * vtmp[j];
    }

    // ---- scatter stores
#pragma unroll
    for (int g = 0; g < GTOK; ++g) {
        float* __restrict__ orow = out + (size_t)sperm[g] * OUTF;
#pragma unroll
        for (int jd = 0; jd < 4; ++jd)
#pragma unroll
            for (int jc = 0; jc < 2; ++jc)
                orow[(dgrp + 16 * jd) * 32 + c0 + 16 * jc] = acc[g][jd * 2 + jc];
    }
}

extern "C" void kernel_launch(void* const* d_in, const int* in_sizes, int n_in,
                              void* d_out, int out_size, void* d_ws, size_t ws_size,
                              hipStream_t stream) {
    const float* x   = (const float*)d_in[0];
    const int*   rid = (const int*)d_in[1];
    const float* si  = (const float*)d_in[2];
    const float* so  = (const float*)d_in[3];
    const float* rU  = (const float*)d_in[4];
    const float* rV  = (const float*)d_in[5];
    const float* rg  = (const float*)d_in[6];
    float* out = (float*)d_out;

    int*   perm = (int*)d_ws;                              // 64 KB
    float* t    = (float*)((char*)d_ws + 65536);           // 2.95 MB

    sort_kernel<<<1, 1024, 0, stream>>>(rid, perm);
    t_gemm2<<<NTOK / 64, 512, 0, stream>>>(x, si, t);
    fused4<<<NTOK / GTOK, 256, 0, stream>>>(x, rid, so, rU, rV, rg, t, perm, out);
}

// Round 7
// 494.136 us; speedup vs baseline: 10.1494x; 10.1494x over previous
//
#include <hip/hip_runtime.h>

#define NTOK   16384
#define INF    2048
#define OUTF   2048
#define RANK   45
#define GTOK   8
#define NRULES 64

// ---------------- Kernel 0: sort tokens by rule (single block) ----------------
__global__ __launch_bounds__(1024) void sort_kernel(
    const int* __restrict__ rid, int* __restrict__ perm)
{
    __shared__ int cnt[NRULES];
    __shared__ int cur[NRULES];
    const int tid = threadIdx.x;
    if (tid < NRULES) cnt[tid] = 0;
    __syncthreads();
    for (int i = tid; i < NTOK; i += 1024) atomicAdd(&cnt[rid[i]], 1);
    __syncthreads();
    if (tid == 0) {
        int s = 0;
        for (int r = 0; r < NRULES; ++r) { cur[r] = s; s += cnt[r]; }
    }
    __syncthreads();
    for (int i = tid; i < NTOK; i += 1024) {
        const int r = rid[i];
        const int p = atomicAdd(&cur[r], 1);
        perm[p] = i;
    }
}

// ---------------- Kernel A: t = x @ shared_in  [16384,2048]@[2048,45] ----------------
// (unchanged, measured ~204us) 256 blocks x 512 thr; 64r x 48c; micro 2r x 3c.
__global__ __launch_bounds__(512) void t_gemm2(
    const float* __restrict__ x, const float* __restrict__ si, float* __restrict__ t)
{
    __shared__ float x_t[64][66];
    __shared__ float si_l[64][48];
    const int tid  = threadIdx.x;
    const int rg   = tid & 31, cg = tid >> 5;
    const int row0 = rg * 2, c0 = cg * 3;
    const float4* __restrict__ xg = (const float4*)(x + (size_t)blockIdx.x * 64 * INF);

    if (tid < 64 * 3) si_l[tid / 3][RANK + tid % 3] = 0.f;

    float a00=0.f,a01=0.f,a02=0.f,a10=0.f,a11=0.f,a12=0.f;
    float4 px[2];
    float  ps[6];

#pragma unroll
    for (int s = 0; s < 2; ++s) {
        const int i4 = tid + s * 512;
        px[s] = xg[(i4 >> 4) * (INF / 4) + (i4 & 15)];
    }
#pragma unroll
    for (int s = 0; s < 6; ++s) {
        const int i = tid + s * 512;
        ps[s] = (i < 64 * RANK) ? si[i] : 0.f;
    }

    for (int ch = 0; ch < INF / 64; ++ch) {
#pragma unroll
        for (int s = 0; s < 2; ++s) {
            const int i4 = tid + s * 512;
            const int r = i4 >> 4, kq = (i4 & 15) * 4;
            x_t[kq][r] = px[s].x; x_t[kq + 1][r] = px[s].y;
            x_t[kq + 2][r] = px[s].z; x_t[kq + 3][r] = px[s].w;
        }
#pragma unroll
        for (int s = 0; s < 6; ++s) {
            const int i = tid + s * 512;
            if (i < 64 * RANK) si_l[i / RANK][i % RANK] = ps[s];
        }
        __syncthreads();
        if (ch + 1 < INF / 64) {
            const int k0 = (ch + 1) * 64;
#pragma unroll
            for (int s = 0; s < 2; ++s) {
                const int i4 = tid + s * 512;
                px[s] = xg[(i4 >> 4) * (INF / 4) + (k0 >> 2) + (i4 & 15)];
            }
#pragma unroll
            for (int s = 0; s < 6; ++s) {
                const int i = tid + s * 512;
                ps[s] = (i < 64 * RANK) ? si[(size_t)k0 * RANK + i] : 0.f;
            }
        }
#pragma unroll 4
        for (int k = 0; k < 64; ++k) {
            const float2 xv = *(const float2*)&x_t[k][row0];
            const float s0 = si_l[k][c0], s1 = si_l[k][c0 + 1], s2 = si_l[k][c0 + 2];
            a00 += xv.x * s0; a01 += xv.x * s1; a02 += xv.x * s2;
            a10 += xv.y * s0; a11 += xv.y * s1; a12 += xv.y * s2;
        }
        __syncthreads();
    }

    if (c0 < RANK) {
        float* __restrict__ t0 = t + ((size_t)blockIdx.x * 64 + row0) * RANK + c0;
        t0[0] = a00; t0[1] = a01; t0[2] = a02;
        t0[RANK] = a10; t0[RANK + 1] = a11; t0[RANK + 2] = a12;
    }
}

// ---------------- Kernel B1: out = t @ so  (base only, natural order) ----------------
// Round-2 proven shape: acc[8][8] static, sv[8] per k. No perm, no conditionals.
__global__ __launch_bounds__(256) void base_kernel(
    const float* __restrict__ so, const float* __restrict__ t, float* __restrict__ out)
{
    __shared__ float t_lds[GTOK][RANK + 1];
    const int tid  = threadIdx.x;
    const int n0   = blockIdx.x * GTOK;
    const int c0   = tid & 15;
    const int dgrp = tid >> 4;

    for (int i = tid; i < GTOK * RANK; i += 256) {
        const int g = i / RANK, r = i - g * RANK;
        t_lds[g][r] = t[(size_t)(n0 + g) * RANK + r];
    }

    float acc[GTOK][8];
#pragma unroll
    for (int g = 0; g < GTOK; ++g)
#pragma unroll
        for (int j = 0; j < 8; ++j) acc[g][j] = 0.f;

    __syncthreads();

    for (int k = 0; k < RANK; ++k) {
        float sv[8];
#pragma unroll
        for (int jd = 0; jd < 4; ++jd)
#pragma unroll
            for (int jc = 0; jc < 2; ++jc)
                sv[jd * 2 + jc] = so[(size_t)k * OUTF + (dgrp + 16 * jd) * 32 + c0 + 16 * jc];
#pragma unroll
        for (int g = 0; g < GTOK; ++g) {
            const float tv = t_lds[g][k];
#pragma unroll
            for (int j = 0; j < 8; ++j) acc[g][j] += tv * sv[j];
        }
    }

#pragma unroll
    for (int g = 0; g < GTOK; ++g) {
        float* __restrict__ orow = out + (size_t)(n0 + g) * OUTF;
#pragma unroll
        for (int jd = 0; jd < 4; ++jd)
#pragma unroll
            for (int jc = 0; jc < 2; ++jc)
                orow[(dgrp + 16 * jd) * 32 + c0 + 16 * jc] = acc[g][jd * 2 + jc];
    }
}

// ---------------- Kernel B2: out[perm[g]] += gain * vec(V x U^T) ----------------
// ROLLED token loop (runtime g): only transient regs -> no spill possible.
// Sorted tokens: U/V staged only on rule change. RMW on out (after base_kernel).
__global__ __launch_bounds__(256) void adapter_kernel(
    const float* __restrict__ x, const int* __restrict__ rid_p,
    const float* __restrict__ rU, const float* __restrict__ rV,
    const float* __restrict__ gains, const int* __restrict__ perm,
    float* __restrict__ out)
{
    __shared__ __align__(16) float x_lds[INF];
    __shared__ __align__(16) float xu_t[32][68];
    __shared__ __align__(16) float U_t[32][33];
    __shared__ __align__(16) float V_lds[64][68];
    __shared__ int   sperm[GTOK], srid[GTOK];
    __shared__ float sgain[GTOK];

    const int tid  = threadIdx.x;
    const int p0   = blockIdx.x * GTOK;
    const int c0   = tid & 15;
    const int dgrp = tid >> 4;
    const int cx   = tid & 31;
    const int bg   = tid >> 5;

    if (tid < GTOK) {
        const int i = perm[p0 + tid];
        sperm[tid] = i;
        const int r = rid_p[i];
        srid[tid]  = r;
        sgain[tid] = gains[r];
    }
    __syncthreads();

    for (int g = 0; g < GTOK; ++g) {           // rolled: tiny register state
        const float* __restrict__ xr = x + (size_t)sperm[g] * INF;
        ((float4*)x_lds)[tid]       = ((const float4*)xr)[tid];
        ((float4*)x_lds)[tid + 256] = ((const float4*)xr)[tid + 256];
        const bool newrule = (g == 0) || (srid[g] != srid[g - 1]);   // block-uniform
        if (newrule) {
            const float* __restrict__ Ur = rU + (size_t)srid[g] * 1024;
            const float* __restrict__ Vr = rV + (size_t)srid[g] * 4096;
#pragma unroll
            for (int i = 0; i < 4; ++i) {
                const int ii = tid + i * 256;
                U_t[ii & 31][ii >> 5] = Ur[ii];
            }
#pragma unroll
            for (int i = 0; i < 4; ++i) {
                const int i4 = tid + i * 256;
                *(float4*)&V_lds[i4 >> 4][(i4 & 15) * 4] = ((const float4*)Vr)[i4];
            }
        }
        __syncthreads();

        // xu[b][cx] = sum_a x[b*32+a] * U[cx][a],  b = bg*8 + jj
        float xacc[8];
#pragma unroll
        for (int jj = 0; jj < 8; ++jj) xacc[jj] = 0.f;
        for (int aa = 0; aa < 32; aa += 4) {
            const float u0 = U_t[aa][cx], u1 = U_t[aa + 1][cx];
            const float u2 = U_t[aa + 2][cx], u3 = U_t[aa + 3][cx];
#pragma unroll
            for (int jj = 0; jj < 8; ++jj) {
                const float4 xv = *(const float4*)&x_lds[(bg * 8 + jj) * 32 + aa];
                xacc[jj] += xv.x * u0 + xv.y * u1 + xv.z * u2 + xv.w * u3;
            }
        }
#pragma unroll
        for (int jj = 0; jj < 8; ++jj) xu_t[cx][bg * 8 + jj] = xacc[jj];
        __syncthreads();

        // vxu[d][c] = sum_b V[d][b] * xu[b][c]; out[d*32+c] += gain*vxu
        float vtmp[8];
#pragma unroll
        for (int j = 0; j < 8; ++j) vtmp[j] = 0.f;
        for (int b = 0; b < 64; b += 4) {
            const float4 xc0 = *(const float4*)&xu_t[c0][b];
            const float4 xc1 = *(const float4*)&xu_t[c0 + 16][b];
#pragma unroll
            for (int jd = 0; jd < 4; ++jd) {
                const float4 vv = *(const float4*)&V_lds[dgrp + 16 * jd][b];
                vtmp[jd * 2]     += vv.x * xc0.x + vv.y * xc0.y + vv.z * xc0.z + vv.w * xc0.w;
                vtmp[jd * 2 + 1] += vv.x * xc1.x + vv.y * xc1.y + vv.z * xc1.z + vv.w * xc1.w;
            }
        }
        const float gn = sgain[g];
        float* __restrict__ orow = out + (size_t)sperm[g] * OUTF;
#pragma unroll
        for (int jd = 0; jd < 4; ++jd)
#pragma unroll
            for (int jc = 0; jc < 2; ++jc) {
                const int idx = (dgrp + 16 * jd) * 32 + c0 + 16 * jc;
                orow[idx] += gn * vtmp[jd * 2 + jc];
            }
        __syncthreads();   // LDS free for next iteration's staging
    }
}

extern "C" void kernel_launch(void* const* d_in, const int* in_sizes, int n_in,
                              void* d_out, int out_size, void* d_ws, size_t ws_size,
                              hipStream_t stream) {
    const float* x   = (const float*)d_in[0];
    const int*   rid = (const int*)d_in[1];
    const float* si  = (const float*)d_in[2];
    const float* so  = (const float*)d_in[3];
    const float* rU  = (const float*)d_in[4];
    const float* rV  = (const float*)d_in[5];
    const float* rg  = (const float*)d_in[6];
    float* out = (float*)d_out;

    int*   perm = (int*)d_ws;                              // 64 KB
    float* t    = (float*)((char*)d_ws + 65536);           // 2.95 MB

    sort_kernel<<<1, 1024, 0, stream>>>(rid, perm);
    t_gemm2<<<NTOK / 64, 512, 0, stream>>>(x, si, t);
    base_kernel<<<NTOK / GTOK, 256, 0, stream>>>(so, t, out);
    adapter_kernel<<<NTOK / GTOK, 256, 0, stream>>>(x, rid, rU, rV, rg, perm, out);
}